// Round 7
// baseline (47.017 us; speedup 1.0000x reference)
//
#include <hip/hip_runtime.h>

#define NG  8
#define DH  8
#define KS  7
#define PAD 3
#define TH  16    // tile rows
#define TW  16    // tile cols
#define CH  64
#define HH  64
#define WW  64
#define LST 24    // LDS row stride in words
#define PL  532   // plane stride in words (22*24 + 4)

__device__ __forceinline__ int imin(int a, int b) { return a < b ? a : b; }
__device__ __forceinline__ int imax(int a, int b) { return a > b ? a : b; }

__global__ __launch_bounds__(256, 3)
void saconv_kernel(const float* __restrict__ x,
                   const float* __restrict__ wq,
                   const float* __restrict__ wk,
                   const float* __restrict__ wv,
                   const float* __restrict__ relh,
                   const float* __restrict__ relw,
                   float* __restrict__ out) {
  // xs[ci*PL + row*LST + col] = x[b, g*8+ci, h0+row-3, w0+col-3], f32
  __shared__ float xs[DH * PL];   // ~17 KB

  const int tx    = threadIdx.x;     // 0..7  : pair of output columns
  const int ihalf = threadIdx.y;     // 0..1  : window-row half (i-split)
  const int ty    = threadIdx.z;     // 0..15 : output row
  const int tid   = tx + 8 * ihalf + 16 * ty;   // partner = lane^8 (same wave)
  const int bz = blockIdx.z;
  const int b  = bz >> 3;
  const int g  = bz & 7;
  const int h0 = blockIdx.y * TH;
  const int w0 = blockIdx.x * TW;

  // ---- stage zero-padded x tile as float4 chunks ----
  const float* xb = x + (size_t)(b * CH + g * DH) * (HH * WW);
  #pragma unroll
  for (int kk = 0; kk < 5; kk++) {
    int f = tid + kk * 256;
    if (f < 1056) {                   // 8 planes * 22 rows * 6 float4-cols
      int ci  = f / 132;
      int r   = f - ci * 132;
      int row = r / 6;
      int c4  = r - row * 6;
      int yy  = h0 + row - PAD;
      int cy  = imin(imax(yy, 0), HH - 1);
      bool yok = (yy >= 0) & (yy < HH);
      float v[4];
      #pragma unroll
      for (int e = 0; e < 4; e++) {
        int xx = w0 + 4 * c4 + e - PAD;
        int cx = imin(imax(xx, 0), WW - 1);
        bool inb = yok & (xx >= 0) & (xx < WW);
        float t = xb[((size_t)ci * HH + cy) * WW + cx];
        v[e] = inb ? t : 0.0f;
      }
      *(float4*)(&xs[ci * PL + row * LST + 4 * c4]) = make_float4(v[0], v[1], v[2], v[3]);
    }
  }
  __syncthreads();

  // ---- preamble: q, fold qk = scale*Wk^T q, rq = scale*rel^T q ----
  // Weights read directly from global with wave-uniform indices -> s_load.
  const float scale = 0.35355339059327373f;   // sqrt(1/8)
  float qk[2][DH];
  float rq[2][8];                             // [7] exists only as static-index headroom
  {
    float xc[2][DH];
    #pragma unroll
    for (int o = 0; o < 2; o++)
      #pragma unroll
      for (int ci = 0; ci < DH; ci++)
        xc[o][ci] = xs[ci * PL + (ty + PAD) * LST + (2 * tx + o + PAD)];
    float q_[2][DH];
    #pragma unroll
    for (int o = 0; o < 2; o++)
      #pragma unroll
      for (int c = 0; c < DH; c++) {
        float a = 0.f;
        #pragma unroll
        for (int ci = 0; ci < DH; ci++)
          a = fmaf(wq[(g * DH + c) * DH + ci], xc[o][ci], a);
        q_[o][c] = a;
      }
    #pragma unroll
    for (int o = 0; o < 2; o++)
      #pragma unroll
      for (int ci = 0; ci < DH; ci++) {
        float a = 0.f;
        #pragma unroll
        for (int c = 0; c < DH; c++)
          a = fmaf(q_[o][c], wk[(g * DH + c) * DH + ci], a);
        qk[o][ci] = a * scale;
      }
    #pragma unroll
    for (int o = 0; o < 2; o++) {
      #pragma unroll
      for (int t = 0; t < KS; t++) {
        float a = 0.f;
        #pragma unroll
        for (int c = 0; c < DH; c++) {
          float rv = (g < 4) ? relh[(g * DH + c) * KS + t]
                             : relw[((g - 4) * DH + c) * KS + t];
          a = fmaf(q_[o][c], rv, a);
        }
        rq[o][t] = a * scale;
      }
      rq[o][7] = 0.f;
    }
  }

  // ---- window loop, i-split: ihalf=0 -> i=0..3, ihalf=1 -> i=4..6 ----
  const bool useI = (g < 4);
  float s[2] = {0.f, 0.f};
  float xa[2][DH];
  #pragma unroll
  for (int o = 0; o < 2; o++)
    #pragma unroll
    for (int ci = 0; ci < DH; ci++) xa[o][ci] = 0.f;

  #pragma unroll
  for (int u = 0; u < 4; u++) {
    if (4 * ihalf + u < KS) {
      const int row = ty + 4 * ihalf + u;
      // 8 words (cols 2tx .. 2tx+7) per channel plane: 4x ds_read_b64 each
      float xr[DH][8];
      #pragma unroll
      for (int ci = 0; ci < DH; ci++) {
        const float* bp = &xs[ci * PL + row * LST + 2 * tx];
        float2 a0 = *(const float2*)(bp);
        float2 a1 = *(const float2*)(bp + 2);
        float2 a2 = *(const float2*)(bp + 4);
        float2 a3 = *(const float2*)(bp + 6);
        xr[ci][0] = a0.x; xr[ci][1] = a0.y; xr[ci][2] = a1.x; xr[ci][3] = a1.y;
        xr[ci][4] = a2.x; xr[ci][5] = a2.y; xr[ci][6] = a3.x; xr[ci][7] = a3.y;
      }
      #pragma unroll
      for (int o = 0; o < 2; o++) {
        float e[KS], se = 0.f;
        #pragma unroll
        for (int j = 0; j < KS; j++) {
          float d = useI ? (ihalf ? rq[o][imin(4 + u, 7)] : rq[o][u]) : rq[o][j];
          #pragma unroll
          for (int ci = 0; ci < DH; ci++)
            d = fmaf(qk[o][ci], xr[ci][o + j], d);
          e[j] = __expf(d);
          se += e[j];
        }
        s[o] += se;
        #pragma unroll
        for (int ci = 0; ci < DH; ci++) {
          float a = xa[o][ci];
          #pragma unroll
          for (int j = 0; j < KS; j++)
            a = fmaf(e[j], xr[ci][o + j], a);
          xa[o][ci] = a;
        }
      }
    }
  }

  // ---- combine halves (single exchange; exact since no max-shift) ----
  float xav[2][DH];
  float inv[2];
  #pragma unroll
  for (int o = 0; o < 2; o++) {
    float st = s[o] + __shfl_xor(s[o], 8, 64);
    inv[o] = 1.0f / st;
  }
  #pragma unroll
  for (int o = 0; o < 2; o++)
    #pragma unroll
    for (int ci = 0; ci < DH; ci++) {
      float t_ = xa[o][ci];
      xav[o][ci] = (t_ + __shfl_xor(t_, 8, 64)) * inv[o];
    }

  // ---- epilogue: out = Wv * xav (uniform s_load weights, all 8 c computed);
  //      each half stores its 4 channels with static indices ----
  float ov[2][DH];
  #pragma unroll
  for (int o = 0; o < 2; o++)
    #pragma unroll
    for (int c = 0; c < DH; c++) {
      float a = 0.f;
      #pragma unroll
      for (int ci = 0; ci < DH; ci++)
        a = fmaf(wv[(g * DH + c) * DH + ci], xav[o][ci], a);
      ov[o][c] = a;
    }

  const int h = h0 + ty;
  const int wb = w0 + 2 * tx;
  float* ob = out + (((size_t)(b * CH + g * DH) * HH + h) * WW + wb);
  if (ihalf == 0) {
    #pragma unroll
    for (int n = 0; n < 4; n++)
      *(float2*)(ob + (size_t)n * (HH * WW)) = make_float2(ov[0][n], ov[1][n]);
  } else {
    #pragma unroll
    for (int n = 0; n < 4; n++)
      *(float2*)(ob + (size_t)(4 + n) * (HH * WW)) = make_float2(ov[0][4 + n], ov[1][4 + n]);
  }
}

extern "C" void kernel_launch(void* const* d_in, const int* in_sizes, int n_in,
                              void* d_out, int out_size, void* d_ws, size_t ws_size,
                              hipStream_t stream) {
  const float* x    = (const float*)d_in[0];
  // d_in[1] = r, unused by the reference computation
  const float* wq   = (const float*)d_in[2];
  const float* wk   = (const float*)d_in[3];
  const float* wv   = (const float*)d_in[4];
  const float* relh = (const float*)d_in[5];
  const float* relw = (const float*)d_in[6];
  float* out = (float*)d_out;

  const int B = in_sizes[0] / (CH * HH * WW);   // 8
  dim3 grid(WW / TW, HH / TH, B * NG);          // 4 x 4 x 64 = 1024 blocks
  dim3 block(8, 2, 16);                         // 256 threads = 4 waves
  saconv_kernel<<<grid, block, 0, stream>>>(x, wq, wk, wv, relh, relw, out);
}

// Round 8
// 29.630 us; speedup vs baseline: 1.5868x; 1.5868x over previous
//
#include <hip/hip_runtime.h>

#define NG  8
#define DH  8
#define KS  7
#define PAD 3
#define TH  16    // tile rows
#define TW  16    // tile cols
#define CH  64
#define HH  64
#define WW  64
#define LST 26    // row stride in words: b64 pair-step 13, coprime 16 -> spread
#define PL  574   // plane stride in words (22*26 + 2)

__device__ __forceinline__ int imin(int a, int b) { return a < b ? a : b; }
__device__ __forceinline__ int imax(int a, int b) { return a > b ? a : b; }

__global__ __launch_bounds__(256, 2)   // cap 128 VGPR (proven sane step)
void saconv_kernel(const float* __restrict__ x,
                   const float* __restrict__ wq,
                   const float* __restrict__ wk,
                   const float* __restrict__ wv,
                   const float* __restrict__ relh,
                   const float* __restrict__ relw,
                   float* __restrict__ out) {
  // xs[ci*PL + row*LST + col] = x[b, g*8+ci, h0+row-3, w0+col-3], f32
  __shared__ float xs[DH * PL];   // ~17.9 KB

  const int tx  = threadIdx.x;   // 0..7  : pair of output columns
  const int jh  = threadIdx.y;   // 0..1  : window-COLUMN half (j-split)
  const int ty  = threadIdx.z;   // 0..15 : output row
  const int tid = tx + 8 * jh + 16 * ty;   // partner = lane^8 (same wave)
  const int bz = blockIdx.z;
  const int b  = bz >> 3;
  const int g  = bz & 7;
  const int h0 = blockIdx.y * TH;
  const int w0 = blockIdx.x * TW;

  // ---- stage zero-padded x tile (float2 writes; stride 26 keeps 8B align) ----
  const float* xb = x + (size_t)(b * CH + g * DH) * (HH * WW);
  #pragma unroll
  for (int kk = 0; kk < 9; kk++) {
    int f = tid + kk * 256;
    if (kk < 8 || f < 2112) {          // 8 planes * 22 rows * 12 float2-cols
      int ci  = f / 264;
      int r   = f - ci * 264;
      int row = r / 12;
      int c2  = r - row * 12;
      int yy  = h0 + row - PAD;
      int cy  = imin(imax(yy, 0), HH - 1);
      bool yok = (yy >= 0) & (yy < HH);
      float v[2];
      #pragma unroll
      for (int e = 0; e < 2; e++) {
        int xx = w0 + 2 * c2 + e - PAD;
        int cx = imin(imax(xx, 0), WW - 1);
        bool inb = yok & (xx >= 0) & (xx < WW);
        float t = xb[((size_t)ci * HH + cy) * WW + cx];
        v[e] = inb ? t : 0.0f;
      }
      *(float2*)(&xs[ci * PL + row * LST + 2 * c2]) = make_float2(v[0], v[1]);
    }
  }
  __syncthreads();

  // ---- preamble: q, fold qk = scale*Wk^T q, rr = scale*rel^T q ----
  const float scale = 0.35355339059327373f;   // sqrt(1/8)
  const bool useI = (g < 4);
  float qk[2][DH];
  float rr[2][KS];   // useI: rr[o][i] (7); useJ: rr[o][jj] (4, own j-half)
  {
    float xc[2][DH];
    #pragma unroll
    for (int o = 0; o < 2; o++)
      #pragma unroll
      for (int ci = 0; ci < DH; ci++)
        xc[o][ci] = xs[ci * PL + (ty + PAD) * LST + (2 * tx + o + PAD)];
    float q_[2][DH];
    #pragma unroll
    for (int o = 0; o < 2; o++)
      #pragma unroll
      for (int c = 0; c < DH; c++) {
        float a = 0.f;
        #pragma unroll
        for (int ci = 0; ci < DH; ci++)
          a = fmaf(wq[(g * DH + c) * DH + ci], xc[o][ci], a);
        q_[o][c] = a;
      }
    #pragma unroll
    for (int o = 0; o < 2; o++)
      #pragma unroll
      for (int ci = 0; ci < DH; ci++) {
        float a = 0.f;
        #pragma unroll
        for (int c = 0; c < DH; c++)
          a = fmaf(q_[o][c], wk[(g * DH + c) * DH + ci], a);
        qk[o][ci] = a * scale;
      }
    if (useI) {
      // fold over ALL window rows i (uniform s_load addresses)
      #pragma unroll
      for (int o = 0; o < 2; o++)
        #pragma unroll
        for (int t = 0; t < KS; t++) {
          float a = 0.f;
          #pragma unroll
          for (int c = 0; c < DH; c++)
            a = fmaf(q_[o][c], relh[(g * DH + c) * KS + t], a);
          rr[o][t] = a * scale;
        }
    } else {
      // fold only own j-half (per-lane loads, L1-cached; clamp dummy j=7)
      #pragma unroll
      for (int o = 0; o < 2; o++) {
        #pragma unroll
        for (int jj = 0; jj < 4; jj++) {
          int j = imin(4 * jh + jj, KS - 1);
          float a = 0.f;
          #pragma unroll
          for (int c = 0; c < DH; c++)
            a = fmaf(q_[o][c], relw[((g - 4) * DH + c) * KS + j], a);
          rr[o][jj] = a * scale;
        }
        #pragma unroll
        for (int t = 4; t < KS; t++) rr[o][t] = 0.f;
      }
    }
  }

  // ---- window loop: all 7 rows, own 4 window-cols (jh=1: 3 + masked dummy) ----
  float s[2] = {0.f, 0.f};
  float xa[2][DH];
  #pragma unroll
  for (int o = 0; o < 2; o++)
    #pragma unroll
    for (int ci = 0; ci < DH; ci++) xa[o][ci] = 0.f;

  const int cbase = 2 * tx + 4 * jh;   // LDS col base for this half's windows

  #pragma unroll
  for (int i = 0; i < KS; i++) {
    const int row = ty + i;
    // 5 cols per channel: 2x ds_read_b64 + 1x ds_read_b32
    float xr[DH][5];
    #pragma unroll
    for (int ci = 0; ci < DH; ci++) {
      const float* bp = &xs[ci * PL + row * LST + cbase];
      float2 a0 = *(const float2*)(bp);
      float2 a1 = *(const float2*)(bp + 2);
      xr[ci][0] = a0.x; xr[ci][1] = a0.y; xr[ci][2] = a1.x; xr[ci][3] = a1.y;
      xr[ci][4] = bp[4];
    }
    #pragma unroll
    for (int o = 0; o < 2; o++) {
      #pragma unroll
      for (int jj = 0; jj < 4; jj++) {
        float d = useI ? rr[o][i] : rr[o][jj];
        #pragma unroll
        for (int ci = 0; ci < DH; ci++)
          d = fmaf(qk[o][ci], xr[ci][o + jj], d);
        float e = __expf(d);
        if (jj == 3) e = (jh == 0) ? e : 0.f;   // mask dummy j=7
        s[o] += e;
        #pragma unroll
        for (int ci = 0; ci < DH; ci++)
          xa[o][ci] = fmaf(e, xr[ci][o + jj], xa[o][ci]);
      }
    }
  }

  // ---- combine j-halves (single end exchange; exact, no max-shift) ----
  float xav[2][DH];
  float inv[2];
  #pragma unroll
  for (int o = 0; o < 2; o++) {
    float st = s[o] + __shfl_xor(s[o], 8, 64);
    inv[o] = 1.0f / st;
  }
  #pragma unroll
  for (int o = 0; o < 2; o++)
    #pragma unroll
    for (int ci = 0; ci < DH; ci++) {
      float t_ = xa[o][ci];
      xav[o][ci] = (t_ + __shfl_xor(t_, 8, 64)) * inv[o];
    }

  // ---- epilogue: out = Wv * xav (uniform s_load weights);
  //      each half stores 4 channels with static indices ----
  float ov[2][DH];
  #pragma unroll
  for (int o = 0; o < 2; o++)
    #pragma unroll
    for (int c = 0; c < DH; c++) {
      float a = 0.f;
      #pragma unroll
      for (int ci = 0; ci < DH; ci++)
        a = fmaf(wv[(g * DH + c) * DH + ci], xav[o][ci], a);
      ov[o][c] = a;
    }

  const int h = h0 + ty;
  const int wb = w0 + 2 * tx;
  float* ob = out + (((size_t)(b * CH + g * DH) * HH + h) * WW + wb);
  if (jh == 0) {
    #pragma unroll
    for (int n = 0; n < 4; n++)
      *(float2*)(ob + (size_t)n * (HH * WW)) = make_float2(ov[0][n], ov[1][n]);
  } else {
    #pragma unroll
    for (int n = 0; n < 4; n++)
      *(float2*)(ob + (size_t)(4 + n) * (HH * WW)) = make_float2(ov[0][4 + n], ov[1][4 + n]);
  }
}

extern "C" void kernel_launch(void* const* d_in, const int* in_sizes, int n_in,
                              void* d_out, int out_size, void* d_ws, size_t ws_size,
                              hipStream_t stream) {
  const float* x    = (const float*)d_in[0];
  // d_in[1] = r, unused by the reference computation
  const float* wq   = (const float*)d_in[2];
  const float* wk   = (const float*)d_in[3];
  const float* wv   = (const float*)d_in[4];
  const float* relh = (const float*)d_in[5];
  const float* relw = (const float*)d_in[6];
  float* out = (float*)d_out;

  const int B = in_sizes[0] / (CH * HH * WW);   // 8
  dim3 grid(WW / TW, HH / TH, B * NG);          // 4 x 4 x 64 = 1024 blocks
  dim3 block(8, 2, 16);                         // 256 threads = 4 waves
  saconv_kernel<<<grid, block, 0, stream>>>(x, wq, wk, wv, relh, relw, out);
}

// Round 9
// 25.045 us; speedup vs baseline: 1.8773x; 1.1831x over previous
//
#include <hip/hip_runtime.h>

#define NG  8     // groups (heads)
#define DH  8     // channels per group
#define KS  7
#define PAD 3
#define TH  16    // tile height (output rows per block)
#define TW  32    // tile width (output cols per block)
#define OW  2     // outputs per thread along W
#define TPH 22    // padded tile rows (TH + KS - 1)
#define TPW 38    // padded tile cols (TW + KS - 1)
#define LST 40    // LDS row stride in words
#define CH  64
#define HH  64
#define WW  64

__device__ __forceinline__ int imin(int a, int b) { return a < b ? a : b; }
__device__ __forceinline__ int imax(int a, int b) { return a > b ? a : b; }

__global__ __launch_bounds__(256, 1)
void saconv_kernel(const float* __restrict__ x,
                   const float* __restrict__ wq,
                   const float* __restrict__ wk,
                   const float* __restrict__ wv,
                   const float* __restrict__ relh,
                   const float* __restrict__ relw,
                   float* __restrict__ out) {
  __shared__ float xs[DH][TPH * LST];   // zero-padded x tile, 27.5 KB
  __shared__ float swq[DH * DH];
  __shared__ float swk[DH * DH];
  __shared__ float swv[DH * DH];
  __shared__ float srel[DH * KS];       // rel table for this group's channels

  const int tx  = threadIdx.x;          // 0..15 (pair of output columns)
  const int ty  = threadIdx.y;          // 0..15 (output row)
  const int tid = ty * 16 + tx;         // 0..255
  const int bz  = blockIdx.z;
  const int b   = bz >> 3;
  const int g   = bz & 7;
  const int h0  = blockIdx.y * TH;
  const int w0  = blockIdx.x * TW;

  // ---- stage weights + rel table ----
  if (tid < DH * DH) swq[tid] = wq[g * DH * DH + tid];
  else if (tid < 2 * DH * DH) swk[tid - 64] = wk[g * DH * DH + tid - 64];
  else if (tid < 3 * DH * DH) swv[tid - 128] = wv[g * DH * DH + tid - 128];
  else if (tid < 3 * DH * DH + DH * KS) {
    int t2 = tid - 192;
    int c = t2 / KS, t = t2 - c * KS;
    int gc = g * DH + c;               // global channel
    srel[t2] = (g < 4) ? relh[gc * KS + t] : relw[(gc - 32) * KS + t];
  }

  // ---- stage zero-padded x tile as float4 chunks ----
  const float* xb = x + (size_t)(b * CH + g * DH) * (HH * WW);
  const int NF4 = DH * TPH * (LST / 4);   // 8*22*10 = 1760 float4 chunks
  #pragma unroll
  for (int kk = 0; kk < 7; kk++) {
    int f = tid + kk * 256;
    if (f < NF4) {
      int ci  = f / (TPH * 10);
      int r   = f - ci * (TPH * 10);
      int row = r / 10;
      int c4  = r - row * 10;
      int yy  = h0 + row - PAD;
      int cy  = imin(imax(yy, 0), HH - 1);
      bool yok = (yy >= 0) & (yy < HH);
      float v[4];
      #pragma unroll
      for (int e = 0; e < 4; e++) {
        int xx = w0 + 4 * c4 + e - PAD;
        int cx = imin(imax(xx, 0), WW - 1);
        bool inb = yok & (xx >= 0) & (xx < WW);
        float t = xb[(ci * HH + cy) * WW + cx];
        v[e] = inb ? t : 0.0f;
      }
      *(float4*)(&xs[ci][row * LST + 4 * c4]) = make_float4(v[0], v[1], v[2], v[3]);
    }
  }
  __syncthreads();

  // ---- q for this thread's 2 outputs, fold: qk = scale*(Wk^T q), rq = scale*(rel^T q) ----
  const float scale = 0.35355339059327373f;  // sqrt(1/8)
  float qk[OW][DH];
  float rq[OW][KS];
  {
    float q_[OW][DH];
    #pragma unroll
    for (int o = 0; o < OW; o++) {
      float xc[DH];
      #pragma unroll
      for (int ci = 0; ci < DH; ci++)
        xc[ci] = xs[ci][(ty + PAD) * LST + 2 * tx + o + PAD];
      #pragma unroll
      for (int c = 0; c < DH; c++) {
        float a = 0.f;
        #pragma unroll
        for (int ci = 0; ci < DH; ci++)
          a = fmaf(swq[c * DH + ci], xc[ci], a);
        q_[o][c] = a;
      }
    }
    #pragma unroll
    for (int o = 0; o < OW; o++)
      #pragma unroll
      for (int ci = 0; ci < DH; ci++) {
        float a = 0.f;
        #pragma unroll
        for (int c = 0; c < DH; c++)
          a = fmaf(q_[o][c], swk[c * DH + ci], a);
        qk[o][ci] = a * scale;
      }
    #pragma unroll
    for (int o = 0; o < OW; o++)
      #pragma unroll
      for (int t = 0; t < KS; t++) {
        float a = 0.f;
        #pragma unroll
        for (int c = 0; c < DH; c++)
          a = fmaf(q_[o][c], srel[c * KS + t], a);
        rq[o][t] = a * scale;
      }
  }

  // ---- window loop with REGISTER DOUBLE-BUFFER prefetch of the next row ----
  const bool useI = (g < 4);

  float s[OW], xa[OW][DH];
  #pragma unroll
  for (int o = 0; o < OW; o++) {
    s[o] = 0.f;
    #pragma unroll
    for (int ci = 0; ci < DH; ci++) xa[o][ci] = 0.f;
  }

  float xr[2][DH][8];

  // preload row 0 into buffer 0
  {
    const int rowoff = (ty + 0) * LST + 2 * tx;
    #pragma unroll
    for (int ci = 0; ci < DH; ci++) {
      const float* bp = &xs[ci][rowoff];
      float2 a0 = *(const float2*)(bp);
      float2 a1 = *(const float2*)(bp + 2);
      float2 a2 = *(const float2*)(bp + 4);
      float2 a3 = *(const float2*)(bp + 6);
      xr[0][ci][0] = a0.x; xr[0][ci][1] = a0.y; xr[0][ci][2] = a1.x; xr[0][ci][3] = a1.y;
      xr[0][ci][4] = a2.x; xr[0][ci][5] = a2.y; xr[0][ci][6] = a3.x; xr[0][ci][7] = a3.y;
    }
  }

  #pragma unroll
  for (int i = 0; i < KS; i++) {
    const int cur = i & 1;
    const int nxt = cur ^ 1;
    // issue next row's loads BEFORE computing current row (prefetch distance ~1 iter)
    if (i < KS - 1) {
      const int rowoff = (ty + i + 1) * LST + 2 * tx;
      #pragma unroll
      for (int ci = 0; ci < DH; ci++) {
        const float* bp = &xs[ci][rowoff];
        float2 a0 = *(const float2*)(bp);
        float2 a1 = *(const float2*)(bp + 2);
        float2 a2 = *(const float2*)(bp + 4);
        float2 a3 = *(const float2*)(bp + 6);
        xr[nxt][ci][0] = a0.x; xr[nxt][ci][1] = a0.y; xr[nxt][ci][2] = a1.x; xr[nxt][ci][3] = a1.y;
        xr[nxt][ci][4] = a2.x; xr[nxt][ci][5] = a2.y; xr[nxt][ci][6] = a3.x; xr[nxt][ci][7] = a3.y;
      }
    }

    #pragma unroll
    for (int o = 0; o < OW; o++) {
      float e[KS];
      float se = 0.f;
      #pragma unroll
      for (int j = 0; j < KS; j++) {
        float d = useI ? rq[o][i] : rq[o][j];   // scale pre-folded
        #pragma unroll
        for (int ci = 0; ci < DH; ci++)
          d = fmaf(qk[o][ci], xr[cur][ci][o + j], d);
        e[j] = __expf(d);
        se += e[j];
      }
      s[o] += se;
      #pragma unroll
      for (int ci = 0; ci < DH; ci++) {
        float a = xa[o][ci];
        #pragma unroll
        for (int j = 0; j < KS; j++)
          a = fmaf(e[j], xr[cur][ci][o + j], a);
        xa[o][ci] = a;
      }
    }
  }

  // ---- epilogue: out = Wv * (xa / s), float2 stores ----
  #pragma unroll
  for (int o = 0; o < OW; o++) {
    float inv = 1.0f / s[o];
    #pragma unroll
    for (int ci = 0; ci < DH; ci++) xa[o][ci] *= inv;
  }

  const int h = h0 + ty;
  const int wbase = w0 + 2 * tx;
  #pragma unroll
  for (int c = 0; c < DH; c++) {
    float2 v2;
    {
      float a0 = 0.f, a1 = 0.f;
      #pragma unroll
      for (int ci = 0; ci < DH; ci++) {
        a0 = fmaf(swv[c * DH + ci], xa[0][ci], a0);
        a1 = fmaf(swv[c * DH + ci], xa[1][ci], a1);
      }
      v2.x = a0; v2.y = a1;
    }
    *(float2*)(&out[((size_t)(b * CH + g * DH + c) * HH + h) * WW + wbase]) = v2;
  }
}

extern "C" void kernel_launch(void* const* d_in, const int* in_sizes, int n_in,
                              void* d_out, int out_size, void* d_ws, size_t ws_size,
                              hipStream_t stream) {
  const float* x    = (const float*)d_in[0];
  // d_in[1] = r, unused by the reference computation
  const float* wq   = (const float*)d_in[2];
  const float* wk   = (const float*)d_in[3];
  const float* wv   = (const float*)d_in[4];
  const float* relh = (const float*)d_in[5];
  const float* relw = (const float*)d_in[6];
  float* out = (float*)d_out;

  const int B = in_sizes[0] / (CH * HH * WW);   // 8
  dim3 grid(WW / TW, HH / TH, B * NG);          // 2 x 4 x 64 = 512 blocks
  dim3 block(16, 16, 1);                        // 256 threads = 4 waves
  saconv_kernel<<<grid, block, 0, stream>>>(x, wq, wk, wv, relh, relw, out);
}

// Round 10
// 19.669 us; speedup vs baseline: 2.3904x; 1.2733x over previous
//
#include <hip/hip_runtime.h>
#include <math.h>

#define NG  8
#define DH  8
#define NCP 4     // channel pairs
#define KS  7
#define PAD 3
#define TH  16    // tile rows
#define TW  32    // tile cols
#define OW  2     // outputs per thread along W
#define TPH 22    // padded tile rows
#define RSTW 40   // LDS row stride in h2-words (38 cols + 2 pad)
#define PLW  (TPH * RSTW)   // 880 words per cp-plane
#define CH  64
#define HH  64
#define WW  64

typedef __fp16 h2v __attribute__((ext_vector_type(2)));
typedef __fp16 h4v __attribute__((ext_vector_type(4)));

__device__ __forceinline__ int imin(int a, int b) { return a < b ? a : b; }
__device__ __forceinline__ int imax(int a, int b) { return a > b ? a : b; }

__global__ __launch_bounds__(256, 1)
void saconv_kernel(const float* __restrict__ x,
                   const float* __restrict__ wq,
                   const float* __restrict__ wk,
                   const float* __restrict__ wv,
                   const float* __restrict__ relh,
                   const float* __restrict__ relw,
                   float* __restrict__ out) {
  // xs2[cp*PLW + row*RSTW + col] = h2( x[b,g*8+2cp,row',col'], x[b,g*8+2cp+1,row',col'] )
  __shared__ h2v xs2[NCP * PLW];        // 14.1 KB
  __shared__ float swq[DH * DH];
  __shared__ float swk[DH * DH];
  __shared__ float swv[DH * DH];
  __shared__ float srel[DH * KS];

  const int tx  = threadIdx.x;          // 0..15 (pair of output columns)
  const int ty  = threadIdx.y;          // 0..15 (output row)
  const int tid = ty * 16 + tx;
  const int bz  = blockIdx.z;
  const int b   = bz >> 3;
  const int g   = bz & 7;
  const int h0  = blockIdx.y * TH;
  const int w0  = blockIdx.x * TW;

  // ---- stage weights + rel table (R3-verbatim) ----
  if (tid < DH * DH) swq[tid] = wq[g * DH * DH + tid];
  else if (tid < 2 * DH * DH) swk[tid - 64] = wk[g * DH * DH + tid - 64];
  else if (tid < 3 * DH * DH) swv[tid - 128] = wv[g * DH * DH + tid - 128];
  else if (tid < 3 * DH * DH + DH * KS) {
    int t2 = tid - 192;
    int c = t2 / KS, t = t2 - c * KS;
    int gc = g * DH + c;
    srel[t2] = (g < 4) ? relh[gc * KS + t] : relw[(gc - 32) * KS + t];
  }

  // ---- stage zero-padded x tile as f16 channel-pairs (b64 = 2 cols) ----
  const float* xb = x + (size_t)(b * CH + g * DH) * (HH * WW);
  const int NCHK = NCP * TPH * 19;      // 1672 b64 chunks (cols 0..37)
  #pragma unroll
  for (int kk = 0; kk < 7; kk++) {
    int f = tid + kk * 256;
    if (f < NCHK) {
      int cp  = f / (TPH * 19);
      int r   = f - cp * (TPH * 19);
      int row = r / 19;
      int cc  = r - row * 19;
      int yy  = h0 + row - PAD;
      int cy  = imin(imax(yy, 0), HH - 1);
      bool yok = (yy >= 0) & (yy < HH);
      const float* p0 = xb + ((size_t)(2 * cp) * HH + cy) * WW;
      float v0[2], v1[2];
      #pragma unroll
      for (int e = 0; e < 2; e++) {
        int xx = w0 + 2 * cc + e - PAD;
        int cx = imin(imax(xx, 0), WW - 1);
        bool inb = yok & (xx >= 0) & (xx < WW);
        float a0 = p0[cx];
        float a1 = p0[HH * WW + cx];
        v0[e] = inb ? a0 : 0.0f;
        v1[e] = inb ? a1 : 0.0f;
      }
      h2v pk0 = __builtin_amdgcn_cvt_pkrtz(v0[0], v1[0]);   // col 2cc: (ch lo, ch hi)
      h2v pk1 = __builtin_amdgcn_cvt_pkrtz(v0[1], v1[1]);   // col 2cc+1
      h4v w4 = { pk0.x, pk0.y, pk1.x, pk1.y };
      *(h4v*)&xs2[cp * PLW + row * RSTW + 2 * cc] = w4;
    }
  }
  __syncthreads();

  // ---- preamble: q, fold qk = scale*l2e*(Wk^T q) packed f16, rq = scale*l2e*(rel^T q) ----
  const float scale = 0.35355339059327373f;   // sqrt(1/8)
  const float L2E   = 1.4426950408889634f;
  h2v  qkh[OW][NCP];
  float rq[OW][KS];
  {
    float xc[OW][DH];
    #pragma unroll
    for (int o = 0; o < OW; o++)
      #pragma unroll
      for (int cp = 0; cp < NCP; cp++) {
        h2v wv2 = xs2[cp * PLW + (ty + PAD) * RSTW + (2 * tx + o + PAD)];
        xc[o][2 * cp]     = (float)wv2.x;
        xc[o][2 * cp + 1] = (float)wv2.y;
      }
    float q_[OW][DH];
    #pragma unroll
    for (int o = 0; o < OW; o++)
      #pragma unroll
      for (int c = 0; c < DH; c++) {
        float a = 0.f;
        #pragma unroll
        for (int ci = 0; ci < DH; ci++)
          a = fmaf(swq[c * DH + ci], xc[o][ci], a);
        q_[o][c] = a;
      }
    #pragma unroll
    for (int o = 0; o < OW; o++)
      #pragma unroll
      for (int cp = 0; cp < NCP; cp++) {
        float a0 = 0.f, a1 = 0.f;
        #pragma unroll
        for (int c = 0; c < DH; c++) {
          a0 = fmaf(q_[o][c], swk[c * DH + 2 * cp], a0);
          a1 = fmaf(q_[o][c], swk[c * DH + 2 * cp + 1], a1);
        }
        qkh[o][cp] = __builtin_amdgcn_cvt_pkrtz(a0 * (scale * L2E), a1 * (scale * L2E));
      }
    #pragma unroll
    for (int o = 0; o < OW; o++)
      #pragma unroll
      for (int t = 0; t < KS; t++) {
        float a = 0.f;
        #pragma unroll
        for (int c = 0; c < DH; c++)
          a = fmaf(q_[o][c], srel[c * KS + t], a);
        rq[o][t] = a * (scale * L2E);
      }
  }

  // ---- window loop: fdot2 logits (base-2), fma_mix accumulation ----
  const bool useI = (g < 4);

  float s[OW], xa[OW][DH];
  #pragma unroll
  for (int o = 0; o < OW; o++) {
    s[o] = 0.f;
    #pragma unroll
    for (int ci = 0; ci < DH; ci++) xa[o][ci] = 0.f;
  }

  #pragma unroll
  for (int i = 0; i < KS; i++) {
    const int wbase = (ty + i) * RSTW + 2 * tx;
    // 8 consecutive h2-words (cols 2tx..2tx+7) per cp-plane: 4x ds_read_b64
    h2v xw[NCP][8];
    #pragma unroll
    for (int cp = 0; cp < NCP; cp++) {
      const h4v* bp = (const h4v*)&xs2[cp * PLW + wbase];
      h4v r0 = bp[0], r1 = bp[1], r2 = bp[2], r3 = bp[3];
      xw[cp][0] = __builtin_shufflevector(r0, r0, 0, 1);
      xw[cp][1] = __builtin_shufflevector(r0, r0, 2, 3);
      xw[cp][2] = __builtin_shufflevector(r1, r1, 0, 1);
      xw[cp][3] = __builtin_shufflevector(r1, r1, 2, 3);
      xw[cp][4] = __builtin_shufflevector(r2, r2, 0, 1);
      xw[cp][5] = __builtin_shufflevector(r2, r2, 2, 3);
      xw[cp][6] = __builtin_shufflevector(r3, r3, 0, 1);
      xw[cp][7] = __builtin_shufflevector(r3, r3, 2, 3);
    }

    #pragma unroll
    for (int o = 0; o < OW; o++) {
      float e[KS];
      float se = 0.f;
      #pragma unroll
      for (int j = 0; j < KS; j++) {
        float d = useI ? rq[o][i] : rq[o][j];   // log2-domain, scale pre-folded
        #pragma unroll
        for (int cp = 0; cp < NCP; cp++)
          d = __builtin_amdgcn_fdot2(qkh[o][cp], xw[cp][o + j], d, false);
        e[j] = exp2f(d);
        se += e[j];
      }
      s[o] += se;
      #pragma unroll
      for (int cp = 0; cp < NCP; cp++) {
        float a0 = xa[o][2 * cp];
        float a1 = xa[o][2 * cp + 1];
        #pragma unroll
        for (int j = 0; j < KS; j++) {
          a0 = fmaf(e[j], (float)xw[cp][o + j].x, a0);   // v_fma_mix_f32
          a1 = fmaf(e[j], (float)xw[cp][o + j].y, a1);
        }
        xa[o][2 * cp]     = a0;
        xa[o][2 * cp + 1] = a1;
      }
    }
  }

  // ---- epilogue: out = Wv * (xa / s), float2 stores (R3-verbatim) ----
  #pragma unroll
  for (int o = 0; o < OW; o++) {
    float inv = 1.0f / s[o];
    #pragma unroll
    for (int ci = 0; ci < DH; ci++) xa[o][ci] *= inv;
  }

  const int h = h0 + ty;
  const int wbase = w0 + 2 * tx;
  #pragma unroll
  for (int c = 0; c < DH; c++) {
    float2 v2;
    {
      float a0 = 0.f, a1 = 0.f;
      #pragma unroll
      for (int ci = 0; ci < DH; ci++) {
        a0 = fmaf(swv[c * DH + ci], xa[0][ci], a0);
        a1 = fmaf(swv[c * DH + ci], xa[1][ci], a1);
      }
      v2.x = a0; v2.y = a1;
    }
    *(float2*)(&out[((size_t)(b * CH + g * DH + c) * HH + h) * WW + wbase]) = v2;
  }
}

extern "C" void kernel_launch(void* const* d_in, const int* in_sizes, int n_in,
                              void* d_out, int out_size, void* d_ws, size_t ws_size,
                              hipStream_t stream) {
  const float* x    = (const float*)d_in[0];
  // d_in[1] = r, unused by the reference computation
  const float* wq   = (const float*)d_in[2];
  const float* wk   = (const float*)d_in[3];
  const float* wv   = (const float*)d_in[4];
  const float* relh = (const float*)d_in[5];
  const float* relw = (const float*)d_in[6];
  float* out = (float*)d_out;

  const int B = in_sizes[0] / (CH * HH * WW);   // 8
  dim3 grid(WW / TW, HH / TH, B * NG);          // 2 x 4 x 64 = 512 blocks
  dim3 block(16, 16, 1);                        // 256 threads = 4 waves
  saconv_kernel<<<grid, block, 0, stream>>>(x, wq, wk, wv, relh, relw, out);
}